// Round 2
// baseline (267.629 us; speedup 1.0000x reference)
//
#include <hip/hip_runtime.h>
#include <cstdint>

// B=512, D=256, H=512. out: [512,512] fp32.
// ws: Ai [512*512] f32 (pre-scaled C2) | Aj [512*512] f32 ((..+b1)*C2) | W2q [512*512] i8 swizzled

#define NB 512
#define ND 256
#define NH 512
#define C2 2.885390081777927f  // 2*log2(e): tanh(x) = 1 - 2/(exp2(x*C2)+1)

typedef int i32x4 __attribute__((ext_vector_type(4)));
typedef int i32x16 __attribute__((ext_vector_type(16)));
typedef unsigned int u32;
typedef unsigned char u8;

__device__ __forceinline__ float exp2_fast(float x) {
#if __has_builtin(__builtin_amdgcn_exp2f)
  return __builtin_amdgcn_exp2f(x);
#else
  return exp2f(x);
#endif
}
__device__ __forceinline__ float rcp_fast(float x) {
#if __has_builtin(__builtin_amdgcn_rcpf)
  return __builtin_amdgcn_rcpf(x);
#else
  return 1.0f / x;
#endif
}
__device__ __forceinline__ u32 perm_b32(u32 hi, u32 lo, u32 sel) {
#if __has_builtin(__builtin_amdgcn_perm)
  return __builtin_amdgcn_perm(hi, lo, sel);
#else
  u32 r = 0;
  for (int b = 0; b < 4; ++b) {
    const u32 c = (sel >> (8 * b)) & 255;
    const u32 byte = (c < 4) ? (lo >> (8 * c)) & 255 : (c < 8) ? (hi >> (8 * (c - 4))) & 255 : 0;
    r |= byte << (8 * b);
  }
  return r;
#endif
}
// u pre-scaled by C2: float whose low byte = int8(round(127*tanh(u/C2)))
__device__ __forceinline__ u32 tanh_q127_magic(float u) {
  const float r = rcp_fast(exp2_fast(u) + 1.0f);
  // 12583039 = 1.5*2^23 + 127; result = MAGIC + (127 - 254 r), RNE in the fma; low byte = i8 two's-compl.
  return __builtin_bit_cast(u32, fmaf(-254.0f, r, 12583039.0f));
}

// pack 16 values (4 float4 pairs) -> 16 i8 bytes
__device__ __forceinline__ uint4 pack16(const float4* fa, const float4* ga) {
  u32 wds[4];
#pragma unroll
  for (int q = 0; q < 4; ++q) {
    const u32 m0 = tanh_q127_magic(fa[q].x + ga[q].x);
    const u32 m1 = tanh_q127_magic(fa[q].y + ga[q].y);
    const u32 m2 = tanh_q127_magic(fa[q].z + ga[q].z);
    const u32 m3 = tanh_q127_magic(fa[q].w + ga[q].w);
    const u32 p01 = perm_b32(m1, m0, 0x0C0C0400u);
    const u32 p23 = perm_b32(m3, m2, 0x0C0C0400u);
    wds[q] = perm_b32(p23, p01, 0x05040100u);
  }
  return make_uint4(wds[0], wds[1], wds[2], wds[3]);
}

// ---------------- prep v3: blocks 0..255 Ai/Aj GEMM (4 i-rows, n-half); 256..319 W2 -> i8 ----------------
__global__ __launch_bounds__(256) void prep_all(const float* __restrict__ h,
                                                const float* __restrict__ W1,
                                                const float* __restrict__ b1,
                                                const float* __restrict__ W2,
                                                float* __restrict__ Ai,
                                                float* __restrict__ Aj,
                                                u8* __restrict__ W2q) {
  const int t = threadIdx.x;
  const int bx = blockIdx.x;
  if (bx < 256) {
    __shared__ float hsh[4][ND];
    const int i0 = (bx >> 1) * 4;
    const int n = (bx & 1) * 256 + t;
#pragma unroll
    for (int ii = 0; ii < 4; ++ii) hsh[ii][t] = h[(i0 + ii) * ND + t];
    __syncthreads();
    float ai[4] = {0.0f, 0.0f, 0.0f, 0.0f};
    float aj[4] = {0.0f, 0.0f, 0.0f, 0.0f};
#pragma unroll 4
    for (int d = 0; d < ND; ++d) {
      const float wa = W1[d * NH + n];
      const float wb = W1[(d + ND) * NH + n];
#pragma unroll
      for (int ii = 0; ii < 4; ++ii) {
        const float hd = hsh[ii][d];
        ai[ii] = fmaf(hd, wa, ai[ii]);
        aj[ii] = fmaf(hd, wb, aj[ii]);
      }
    }
    const float b1n = b1[n];
#pragma unroll
    for (int ii = 0; ii < 4; ++ii) {
      Ai[(i0 + ii) * NH + n] = ai[ii] * C2;
      Aj[(i0 + ii) * NH + n] = (aj[ii] + b1n) * C2;
    }
  } else {
    // W2 -> i8 (scale 0.25/127), MFMA B-frag order for i8 32x32x32:
    // frag id g = ks*1024 + nt*64 + lane (16 B): byte j = q(W2[ks*32 + (lane>>5)*16 + j][nt*32 + (lane&31)])
    const int g = (bx - 256) * 256 + t;  // 0..16383
    const int lane = g & 63;
    const int nt = (g >> 6) & 15;
    const int ks = g >> 10;
    const int n = nt * 32 + (lane & 31);
    const int kb = ks * 32 + ((lane >> 5) << 4);
    u32 w[4];
#pragma unroll
    for (int q = 0; q < 4; ++q) {
      u32 acc = 0;
#pragma unroll
      for (int j = 0; j < 4; ++j) {
        const float wv = fminf(fmaxf(W2[(kb + q * 4 + j) * NH + n], -0.25f), 0.25f);
        const int qi = (int)rintf(wv * 508.0f);  // 508 = 127/0.25
        acc |= ((u32)(qi & 255)) << (8 * j);
      }
      w[q] = acc;
    }
    ((uint4*)W2q)[g] = make_uint4(w[0], w[1], w[2], w[3]);
  }
}

// ---------------- main v3: weight-stationary persistent blocks ----------------
// Grid 256 = j-tile(16) x i-chunk(16). Block: 512 thr / 8 waves. Wave w owns n-tiles {2w,2w+1}
// (64 n) with B frags register-resident (128 VGPR). Loop over 32 i's:
//   issue Ai(i+1) loads -> K-loop MFMA on xs[buf] -> stage i+1 into xs[buf^1] -> epilogue -> barrier.
// Aj row values (invariant over i) held in 32 persistent VGPRs. One barrier per iter;
// red double-buffered so the cross-wave output reduce uses the previous iter's barrier.
__global__ __launch_bounds__(512, 2) void pair_main(const float* __restrict__ Ai,
                                                    const float* __restrict__ Aj,
                                                    const u8* __restrict__ W2q,
                                                    const float* __restrict__ b2,
                                                    const float* __restrict__ W3,
                                                    const float* __restrict__ b3,
                                                    float* __restrict__ out) {
  __shared__ __align__(16) u8 xs[2][32 * 512];  // 2 x 16 KB
  __shared__ float red[2][8][32];               // 2 KB

  const int t = threadIdx.x;
  const int w = t >> 6;  // 0..7 = n-group
  const int lane = t & 63;
  const int lhi = lane >> 5;
  const int llo = lane & 31;
  const int bx = blockIdx.x;
  const int jt = bx & 15;
  const int ich = bx >> 4;
  const int j0 = jt * 32;
  const int i0 = ich * 32;

  // ---- B prologue: W2q frags -> registers (32 x uint4 = 128 VGPR) ----
  i32x4 Bf[16][2];
  {
    const uint4* w2v = (const uint4*)W2q + w * 128 + lane;  // + ks*1024, +64 for ntl=1
#pragma unroll
    for (int ks = 0; ks < 16; ++ks) {
      Bf[ks][0] = __builtin_bit_cast(i32x4, w2v[ks * 1024]);
      Bf[ks][1] = __builtin_bit_cast(i32x4, w2v[ks * 1024 + 64]);
    }
  }

  // ---- epilogue invariants ----
  const float SCALE = (0.25f / (127.0f * 127.0f)) * C2;
  float b2c[2], w3v[2];
#pragma unroll
  for (int ntl = 0; ntl < 2; ++ntl) {
    const int n = w * 64 + ntl * 32 + llo;
    b2c[ntl] = b2[n] * C2;
    w3v[ntl] = W3[n];
  }
  float w3s = w3v[0] + w3v[1];
#pragma unroll
  for (int off = 1; off < 32; off <<= 1) w3s += __shfl_xor(w3s, off, 64);
  const float b3v = b3[0];

  // ---- staging geometry: thread t -> row = t&31, slots {t>>5, (t>>5)+16} ----
  const int srow = t & 31;
  const int ss0 = t >> 5;  // 0..15
  const int k0 = ss0 * 16;

  // Aj row values: invariant across the i-loop -> persistent registers (8 float4)
  float4 fj[8];
  {
    const float* ajr = Aj + (size_t)(j0 + srow) * NH;
#pragma unroll
    for (int q = 0; q < 4; ++q) {
      fj[q] = *(const float4*)(ajr + k0 + q * 4);
      fj[q + 4] = *(const float4*)(ajr + k0 + 256 + q * 4);
    }
  }

  // ---- prologue: stage i0 into xs[0] ----
  {
    const float* air = Ai + (size_t)i0 * NH;
    float4 gi[8];
#pragma unroll
    for (int q = 0; q < 4; ++q) {
      gi[q] = *(const float4*)(air + k0 + q * 4);
      gi[q + 4] = *(const float4*)(air + k0 + 256 + q * 4);
    }
    ((uint4*)xs[0])[ss0 * 32 + srow] = pack16(fj, gi);
    ((uint4*)xs[0])[(ss0 + 16) * 32 + srow] = pack16(fj + 4, gi + 4);
  }
  __syncthreads();

  const int abase = lhi * 32 + llo;

  for (int il = 0; il < 32; ++il) {
    const int buf = il & 1;
    const int i = i0 + il;

    // 1) issue Ai(i+1) loads early (L1/L2 hit; latency hidden under K-loop MFMAs)
    float4 gi[8];
    if (il < 31) {
      const float* air = Ai + (size_t)(i + 1) * NH;
#pragma unroll
      for (int q = 0; q < 4; ++q) {
        gi[q] = *(const float4*)(air + k0 + q * 4);
        gi[q + 4] = *(const float4*)(air + k0 + 256 + q * 4);
      }
    }

    // 2) K-loop: 16 ks, B from registers, A from LDS
    i32x16 acc[2];
#pragma unroll
    for (int ntl = 0; ntl < 2; ++ntl)
#pragma unroll
      for (int q = 0; q < 16; ++q) acc[ntl][q] = 0;
    {
      const i32x4* xv = (const i32x4*)(xs[buf]);
#pragma unroll
      for (int ks = 0; ks < 16; ++ks) {
        const i32x4 a = xv[ks * 64 + abase];
        acc[0] = __builtin_amdgcn_mfma_i32_32x32x32_i8(a, Bf[ks][0], acc[0], 0, 0, 0);
        acc[1] = __builtin_amdgcn_mfma_i32_32x32x32_i8(a, Bf[ks][1], acc[1], 0, 0, 0);
      }
    }

    // 3) stage i+1 into xs[buf^1]
    if (il < 31) {
      ((uint4*)xs[buf ^ 1])[ss0 * 32 + srow] = pack16(fj, gi);
      ((uint4*)xs[buf ^ 1])[(ss0 + 16) * 32 + srow] = pack16(fj + 4, gi + 4);
    }

    // 4) epilogue: y = acc*SCALE + b2*C2; r = 1/(exp2(y)+1); partial = Σw3 - 2 Σ w3·r
#pragma unroll
    for (int reg = 0; reg < 16; ++reg) {
      float sr = 0.0f;
#pragma unroll
      for (int ntl = 0; ntl < 2; ++ntl) {
        const float y = fmaf((float)acc[ntl][reg], SCALE, b2c[ntl]);
        const float r = rcp_fast(exp2_fast(y) + 1.0f);
        sr = fmaf(w3v[ntl], r, sr);
      }
#pragma unroll
      for (int off = 1; off < 32; off <<= 1) sr += __shfl_xor(sr, off, 64);
      const int row = (reg & 3) + 8 * (reg >> 2) + 4 * lhi;  // 0..31
      if (llo == reg) red[buf][w][row] = fmaf(-2.0f, sr, w3s);
    }

    // 5) out-write for i-1 (red[buf^1] was completed before the previous barrier)
    if (il > 0 && t < 32) {
      float v = b3v;
#pragma unroll
      for (int ww = 0; ww < 8; ++ww) v += red[buf ^ 1][ww][t];
      const int ip = i - 1;
      const int j = j0 + t;
      out[ip * NB + j] = (j == ip) ? -20.0f : v;
    }

    __syncthreads();
  }

  // drain: out for i0+31 (red[1], synced by the loop's final barrier)
  if (t < 32) {
    float v = b3v;
#pragma unroll
    for (int ww = 0; ww < 8; ++ww) v += red[1][ww][t];
    const int ip = i0 + 31;
    const int j = j0 + t;
    out[ip * NB + j] = (j == ip) ? -20.0f : v;
  }
}

extern "C" void kernel_launch(void* const* d_in, const int* in_sizes, int n_in,
                              void* d_out, int out_size, void* d_ws, size_t ws_size,
                              hipStream_t stream) {
  const float* h = (const float*)d_in[0];
  const float* W1 = (const float*)d_in[1];
  const float* b1 = (const float*)d_in[2];
  const float* W2 = (const float*)d_in[3];
  const float* b2 = (const float*)d_in[4];
  const float* W3 = (const float*)d_in[5];
  const float* b3 = (const float*)d_in[6];
  float* out = (float*)d_out;

  float* Ai = (float*)d_ws;
  float* Aj = Ai + NB * NH;
  u8* W2q = (u8*)(Aj + NB * NH);

  prep_all<<<320, 256, 0, stream>>>(h, W1, b1, W2, Ai, Aj, W2q);
  pair_main<<<256, 512, 0, stream>>>(Ai, Aj, W2q, b2, W3, b3, out);
}

// Round 3
// 246.036 us; speedup vs baseline: 1.0878x; 1.0878x over previous
//
#include <hip/hip_runtime.h>
#include <cstdint>

// B=512, D=256, H=512. out: [512,512] fp32.
// ws: Ai [512*512] f32 (pre-scaled C2) | Aj [512*512] f32 ((..+b1)*C2) | W2q [512*512] i8 swizzled

#define NB 512
#define ND 256
#define NH 512
#define C2 2.885390081777927f  // 2*log2(e): tanh(x) = 1 - 2/(exp2(x*C2)+1)

typedef int i32x4 __attribute__((ext_vector_type(4)));
typedef int i32x16 __attribute__((ext_vector_type(16)));
typedef unsigned int u32;
typedef unsigned char u8;

__device__ __forceinline__ float exp2_fast(float x) {
#if __has_builtin(__builtin_amdgcn_exp2f)
  return __builtin_amdgcn_exp2f(x);
#else
  return exp2f(x);
#endif
}
__device__ __forceinline__ float rcp_fast(float x) {
#if __has_builtin(__builtin_amdgcn_rcpf)
  return __builtin_amdgcn_rcpf(x);
#else
  return 1.0f / x;
#endif
}
__device__ __forceinline__ u32 perm_b32(u32 hi, u32 lo, u32 sel) {
#if __has_builtin(__builtin_amdgcn_perm)
  return __builtin_amdgcn_perm(hi, lo, sel);
#else
  u32 r = 0;
  for (int b = 0; b < 4; ++b) {
    const u32 c = (sel >> (8 * b)) & 255;
    const u32 byte = (c < 4) ? (lo >> (8 * c)) & 255 : (c < 8) ? (hi >> (8 * (c - 4))) & 255 : 0;
    r |= byte << (8 * b);
  }
  return r;
#endif
}

// ---------------- prep: blocks 0..255 Ai/Aj GEMM (4 i-rows, n-half); 256..319 W2 -> i8 ----------------
__global__ __launch_bounds__(256) void prep_all(const float* __restrict__ h,
                                                const float* __restrict__ W1,
                                                const float* __restrict__ b1,
                                                const float* __restrict__ W2,
                                                float* __restrict__ Ai,
                                                float* __restrict__ Aj,
                                                u8* __restrict__ W2q) {
  const int t = threadIdx.x;
  const int bx = blockIdx.x;
  if (bx < 256) {
    __shared__ float hsh[4][ND];
    const int i0 = (bx >> 1) * 4;
    const int n = (bx & 1) * 256 + t;
#pragma unroll
    for (int ii = 0; ii < 4; ++ii) hsh[ii][t] = h[(i0 + ii) * ND + t];
    __syncthreads();
    float ai[4] = {0.0f, 0.0f, 0.0f, 0.0f};
    float aj[4] = {0.0f, 0.0f, 0.0f, 0.0f};
#pragma unroll 4
    for (int d = 0; d < ND; ++d) {
      const float wa = W1[d * NH + n];
      const float wb = W1[(d + ND) * NH + n];
#pragma unroll
      for (int ii = 0; ii < 4; ++ii) {
        const float hd = hsh[ii][d];
        ai[ii] = fmaf(hd, wa, ai[ii]);
        aj[ii] = fmaf(hd, wb, aj[ii]);
      }
    }
    const float b1n = b1[n];
#pragma unroll
    for (int ii = 0; ii < 4; ++ii) {
      Ai[(i0 + ii) * NH + n] = ai[ii] * C2;
      Aj[(i0 + ii) * NH + n] = (aj[ii] + b1n) * C2;
    }
  } else {
    // W2 -> i8 (scale 0.25/127), MFMA B-frag order for i8 32x32x32:
    // frag id g = ks*1024 + nt*64 + lane (16 B): byte j = q(W2[ks*32 + (lane>>5)*16 + j][nt*32 + (lane&31)])
    const int g = (bx - 256) * 256 + t;  // 0..16383
    const int lane = g & 63;
    const int nt = (g >> 6) & 15;
    const int ks = g >> 10;
    const int n = nt * 32 + (lane & 31);
    const int kb = ks * 32 + ((lane >> 5) << 4);
    u32 w[4];
#pragma unroll
    for (int q = 0; q < 4; ++q) {
      u32 acc = 0;
#pragma unroll
      for (int j = 0; j < 4; ++j) {
        const float wv = fminf(fmaxf(W2[(kb + q * 4 + j) * NH + n], -0.25f), 0.25f);
        const int qi = (int)rintf(wv * 508.0f);  // 508 = 127/0.25
        acc |= ((u32)(qi & 255)) << (8 * j);
      }
      w[q] = acc;
    }
    ((uint4*)W2q)[g] = make_uint4(w[0], w[1], w[2], w[3]);
  }
}

// ---------------- main v4: round-0 structure + ILP-batched trans + cheap LDS reduce ----------------
// Block: one i, 32 j's, N=512, K=512 (16 ks of 32). 512 thr / 8 waves; wave w: n-tiles {2w,2w+1}.
// Staging and epilogue are batched 32-wide (all adds -> all exp2 -> all rcp -> all packs) so the
// compiler can pipeline trans-latency; target ~96-128 VGPR, 4 waves/SIMD, 2 blocks/CU.
// Epilogue reduce: 2-level shfl fold (groups of 4 llo) -> red2[32][64] LDS -> 512-thread final pass.
__global__ __launch_bounds__(512, 4) void pair_main(const float* __restrict__ Ai,
                                                    const float* __restrict__ Aj,
                                                    const u8* __restrict__ W2q,
                                                    const float* __restrict__ b2,
                                                    const float* __restrict__ W3,
                                                    const float* __restrict__ b3,
                                                    float* __restrict__ out) {
  __shared__ __align__(16) u8 xs[32 * 512];  // 16 KB
  __shared__ float red2[32][64];             // 8 KB
  __shared__ float wsum[8];

  const int t = threadIdx.x;
  const int w = t >> 6;
  const int lane = t & 63;
  const int lhi = lane >> 5;
  const int llo = lane & 31;
  const int bx = blockIdx.x;
  const int i = bx >> 4;
  const int j0 = (bx & 15) * 32;

  // ---- epilogue invariants ----
  const float SCALE = (0.25f / (127.0f * 127.0f)) * C2;
  float b2c[2], w3v[2];
#pragma unroll
  for (int ntl = 0; ntl < 2; ++ntl) {
    const int n = w * 64 + ntl * 32 + llo;
    b2c[ntl] = b2[n] * C2;
    w3v[ntl] = W3[n];
  }
  {
    float w3s = w3v[0] + w3v[1];
#pragma unroll
    for (int off = 1; off < 32; off <<= 1) w3s += __shfl_xor(w3s, off, 64);
    if (lane == 0) wsum[w] = w3s;  // visible after the staging barrier
  }

  // ---- stage X (batched): thread t -> row = t&31, slots {t>>5, (t>>5)+16} (16 k each) ----
  {
    const int srow = t & 31;
    const int ss0 = t >> 5;  // 0..15
    const int k0 = ss0 * 16;
    const float* ajr = Aj + (size_t)(j0 + srow) * NH;
    const float* air = Ai + (size_t)i * NH;
    float s[32];
#pragma unroll
    for (int g = 0; g < 8; ++g) {
      const int ko = k0 + (g & 3) * 4 + (g >> 2) * 256;
      const float4 fa = *(const float4*)(ajr + ko);
      const float4 ga = *(const float4*)(air + ko);
      s[g * 4 + 0] = fa.x + ga.x;
      s[g * 4 + 1] = fa.y + ga.y;
      s[g * 4 + 2] = fa.z + ga.z;
      s[g * 4 + 3] = fa.w + ga.w;
    }
#pragma unroll
    for (int q = 0; q < 32; ++q) s[q] = exp2_fast(s[q]);
#pragma unroll
    for (int q = 0; q < 32; ++q) s[q] = rcp_fast(s[q] + 1.0f);
    u32 m[32];
    // 12583039 = 1.5*2^23 + 127; low byte = i8(127*tanh) via RNE in the fma
#pragma unroll
    for (int q = 0; q < 32; ++q) m[q] = __builtin_bit_cast(u32, fmaf(-254.0f, s[q], 12583039.0f));
    u32 wd[8];
#pragma unroll
    for (int g = 0; g < 8; ++g) {
      const u32 p01 = perm_b32(m[g * 4 + 1], m[g * 4 + 0], 0x0C0C0400u);
      const u32 p23 = perm_b32(m[g * 4 + 3], m[g * 4 + 2], 0x0C0C0400u);
      wd[g] = perm_b32(p23, p01, 0x05040100u);
    }
    ((uint4*)xs)[ss0 * 32 + srow] = make_uint4(wd[0], wd[1], wd[2], wd[3]);
    ((uint4*)xs)[(ss0 + 16) * 32 + srow] = make_uint4(wd[4], wd[5], wd[6], wd[7]);
  }
  __syncthreads();

  // ---- K-loop: ping-pong x2 unroll, prefetch distance 2, B from L2 ----
  i32x16 acc[2];
#pragma unroll
  for (int nt = 0; nt < 2; ++nt)
#pragma unroll
    for (int q = 0; q < 16; ++q) acc[nt][q] = 0;

  const i32x4* xsv = (const i32x4*)xs;
  const int abase = lhi * 32 + llo;                        // + ks*64
  const uint4* w2v = (const uint4*)W2q + w * 128 + lane;   // + ks*1024, +64 for ntl=1

  i32x4 aP0 = xsv[abase];
  i32x4 aP1 = xsv[64 + abase];
  uint4 bP00 = w2v[0], bP01 = w2v[64];
  uint4 bP10 = w2v[1024], bP11 = w2v[1024 + 64];

#pragma unroll
  for (int kk = 0; kk < 8; ++kk) {
    const int ks0 = 2 * kk;
    {
      const i32x4 a = aP0;
      const i32x4 c0 = __builtin_bit_cast(i32x4, bP00);
      const i32x4 c1 = __builtin_bit_cast(i32x4, bP01);
      if (kk < 7) {
        aP0 = xsv[(ks0 + 2) * 64 + abase];
        const uint4* wp = w2v + (ks0 + 2) * 1024;
        bP00 = wp[0];
        bP01 = wp[64];
      }
      acc[0] = __builtin_amdgcn_mfma_i32_32x32x32_i8(a, c0, acc[0], 0, 0, 0);
      acc[1] = __builtin_amdgcn_mfma_i32_32x32x32_i8(a, c1, acc[1], 0, 0, 0);
    }
    {
      const i32x4 a = aP1;
      const i32x4 c0 = __builtin_bit_cast(i32x4, bP10);
      const i32x4 c1 = __builtin_bit_cast(i32x4, bP11);
      if (kk < 7) {
        aP1 = xsv[(ks0 + 3) * 64 + abase];
        const uint4* wp = w2v + (ks0 + 3) * 1024;
        bP10 = wp[0];
        bP11 = wp[64];
      }
      acc[0] = __builtin_amdgcn_mfma_i32_32x32x32_i8(a, c0, acc[0], 0, 0, 0);
      acc[1] = __builtin_amdgcn_mfma_i32_32x32x32_i8(a, c1, acc[1], 0, 0, 0);
    }
  }

  // ---- epilogue (batched): y = acc*SCALE + b2*C2; r = 1/(exp2(y)+1) ----
  float ev[32];
#pragma unroll
  for (int reg = 0; reg < 16; ++reg) {
    ev[reg] = fmaf((float)acc[0][reg], SCALE, b2c[0]);
    ev[16 + reg] = fmaf((float)acc[1][reg], SCALE, b2c[1]);
  }
#pragma unroll
  for (int q = 0; q < 32; ++q) ev[q] = exp2_fast(ev[q]);
#pragma unroll
  for (int q = 0; q < 32; ++q) ev[q] = rcp_fast(ev[q] + 1.0f);

  // partial = Σ_n w3·r ; fold groups of 4 llo lanes, scatter to red2[row][w*8 + llo/4]
#pragma unroll
  for (int reg = 0; reg < 16; ++reg) {
    float sr = fmaf(w3v[0], ev[reg], w3v[1] * ev[16 + reg]);
    sr += __shfl_xor(sr, 1, 64);
    sr += __shfl_xor(sr, 2, 64);
    const int row = (reg & 3) + 8 * (reg >> 2) + 4 * lhi;  // 0..31
    if ((llo & 3) == 0) red2[row][w * 8 + (llo >> 2)] = sr;
  }
  __syncthreads();

  // ---- final reduce: 16 threads per output row ----
  {
    const float w3tot = b3[0] + ((wsum[0] + wsum[1]) + (wsum[2] + wsum[3])) +
                        ((wsum[4] + wsum[5]) + (wsum[6] + wsum[7]));
    const int row = t >> 4;
    const int sub = t & 15;
    const float4 v = *(const float4*)&red2[row][sub * 4];
    float s2 = (v.x + v.y) + (v.z + v.w);
    s2 += __shfl_xor(s2, 1, 16);
    s2 += __shfl_xor(s2, 2, 16);
    s2 += __shfl_xor(s2, 4, 16);
    s2 += __shfl_xor(s2, 8, 16);
    if (sub == 0) {
      const int j = j0 + row;
      out[i * NB + j] = (j == i) ? -20.0f : fmaf(-2.0f, s2, w3tot);
    }
  }
}

extern "C" void kernel_launch(void* const* d_in, const int* in_sizes, int n_in,
                              void* d_out, int out_size, void* d_ws, size_t ws_size,
                              hipStream_t stream) {
  const float* h = (const float*)d_in[0];
  const float* W1 = (const float*)d_in[1];
  const float* b1 = (const float*)d_in[2];
  const float* W2 = (const float*)d_in[3];
  const float* b2 = (const float*)d_in[4];
  const float* W3 = (const float*)d_in[5];
  const float* b3 = (const float*)d_in[6];
  float* out = (float*)d_out;

  float* Ai = (float*)d_ws;
  float* Aj = Ai + NB * NH;
  u8* W2q = (u8*)(Aj + NB * NH);

  prep_all<<<320, 256, 0, stream>>>(h, W1, b1, W2, Ai, Aj, W2q);
  pair_main<<<8192, 512, 0, stream>>>(Ai, Aj, W2q, b2, W3, b3, out);
}

// Round 4
// 236.393 us; speedup vs baseline: 1.1321x; 1.0408x over previous
//
#include <hip/hip_runtime.h>
#include <cstdint>

// B=512, D=256, H=512. out: [512,512] fp32.
// ws: Ai [512*512] f32 (pre-scaled C2) | Aj [512*512] f32 ((..+b1)*C2) | W2q [512*512] i8 swizzled

#define NB 512
#define ND 256
#define NH 512
#define C2 2.885390081777927f  // 2*log2(e): tanh(x) = 1 - 2/(exp2(x*C2)+1)

typedef int i32x4 __attribute__((ext_vector_type(4)));
typedef int i32x16 __attribute__((ext_vector_type(16)));
typedef unsigned int u32;
typedef unsigned char u8;

__device__ __forceinline__ float exp2_fast(float x) {
#if __has_builtin(__builtin_amdgcn_exp2f)
  return __builtin_amdgcn_exp2f(x);
#else
  return exp2f(x);
#endif
}
__device__ __forceinline__ float rcp_fast(float x) {
#if __has_builtin(__builtin_amdgcn_rcpf)
  return __builtin_amdgcn_rcpf(x);
#else
  return 1.0f / x;
#endif
}
__device__ __forceinline__ u32 perm_b32(u32 hi, u32 lo, u32 sel) {
#if __has_builtin(__builtin_amdgcn_perm)
  return __builtin_amdgcn_perm(hi, lo, sel);
#else
  u32 r = 0;
  for (int b = 0; b < 4; ++b) {
    const u32 c = (sel >> (8 * b)) & 255;
    const u32 byte = (c < 4) ? (lo >> (8 * c)) & 255 : (c < 8) ? (hi >> (8 * (c - 4))) & 255 : 0;
    r |= byte << (8 * b);
  }
  return r;
#endif
}
// u pre-scaled by C2: float whose low byte = int8(round(127*tanh(u/C2)))
__device__ __forceinline__ u32 tanh_q127_magic(float u) {
  const float r = rcp_fast(exp2_fast(u) + 1.0f);
  // 12583039 = 1.5*2^23 + 127; result = MAGIC + (127 - 254 r), RNE in the fma; low byte = i8 two's-compl.
  return __builtin_bit_cast(u32, fmaf(-254.0f, r, 12583039.0f));
}

// ---------------- prep: blocks 0..255 Ai/Aj GEMM (4 i-rows, n-half); 256..319 W2 -> i8 ----------------
__global__ __launch_bounds__(256) void prep_all(const float* __restrict__ h,
                                                const float* __restrict__ W1,
                                                const float* __restrict__ b1,
                                                const float* __restrict__ W2,
                                                float* __restrict__ Ai,
                                                float* __restrict__ Aj,
                                                u8* __restrict__ W2q) {
  const int t = threadIdx.x;
  const int bx = blockIdx.x;
  if (bx < 256) {
    __shared__ float hsh[4][ND];
    const int i0 = (bx >> 1) * 4;
    const int n = (bx & 1) * 256 + t;
#pragma unroll
    for (int ii = 0; ii < 4; ++ii) hsh[ii][t] = h[(i0 + ii) * ND + t];
    __syncthreads();
    float ai[4] = {0.0f, 0.0f, 0.0f, 0.0f};
    float aj[4] = {0.0f, 0.0f, 0.0f, 0.0f};
#pragma unroll 4
    for (int d = 0; d < ND; ++d) {
      const float wa = W1[d * NH + n];
      const float wb = W1[(d + ND) * NH + n];
#pragma unroll
      for (int ii = 0; ii < 4; ++ii) {
        const float hd = hsh[ii][d];
        ai[ii] = fmaf(hd, wa, ai[ii]);
        aj[ii] = fmaf(hd, wb, aj[ii]);
      }
    }
    const float b1n = b1[n];
#pragma unroll
    for (int ii = 0; ii < 4; ++ii) {
      Ai[(i0 + ii) * NH + n] = ai[ii] * C2;
      Aj[(i0 + ii) * NH + n] = (aj[ii] + b1n) * C2;
    }
  } else {
    // W2 -> i8 (scale 0.25/127), MFMA B-frag order for i8 32x32x32:
    // frag id g = ks*1024 + nt*64 + lane (16 B): byte j = q(W2[ks*32 + (lane>>5)*16 + j][nt*32 + (lane&31)])
    const int g = (bx - 256) * 256 + t;  // 0..16383
    const int lane = g & 63;
    const int nt = (g >> 6) & 15;
    const int ks = g >> 10;
    const int n = nt * 32 + (lane & 31);
    const int kb = ks * 32 + ((lane >> 5) << 4);
    u32 w[4];
#pragma unroll
    for (int q = 0; q < 4; ++q) {
      u32 acc = 0;
#pragma unroll
      for (int j = 0; j < 4; ++j) {
        const float wv = fminf(fmaxf(W2[(kb + q * 4 + j) * NH + n], -0.25f), 0.25f);
        const int qi = (int)rintf(wv * 508.0f);  // 508 = 127/0.25
        acc |= ((u32)(qi & 255)) << (8 * j);
      }
      w[q] = acc;
    }
    ((uint4*)W2q)[g] = make_uint4(w[0], w[1], w[2], w[3]);
  }
}

// ---------------- main v5: T=2 i-batch per block ----------------
// Block: 2 i's, 32 j's, N=512, K=512. 512 thr / 8 waves; wave w: n-tiles {2w,2w+1}.
// Per ks: 2 B-loads + 2 A-reads feed 4 MFMAs (acc[i][ntl]) -> L2 demand per MFMA-cy halves
// (W2q stream 256 KB/block now serves 2x MFMA work; ~56 B/cy = per-CU L2 share), B-prefetch
// cover doubles (8 MFMAs ~ 290 cy), 4 independent acc chains. 2 barriers per block (1 per i).
// acc = 64 AGPR; launch_bounds(512,4) caps total regs at 128 -> 4 waves/SIMD, 4 blocks/CU by LDS (~35 KB).
__global__ __launch_bounds__(512, 4) void pair_main(const float* __restrict__ Ai,
                                                    const float* __restrict__ Aj,
                                                    const u8* __restrict__ W2q,
                                                    const float* __restrict__ b2,
                                                    const float* __restrict__ W3,
                                                    const float* __restrict__ b3,
                                                    float* __restrict__ out) {
  __shared__ __align__(16) u8 xs[2][32 * 512];  // 32 KB
  __shared__ float red[2][8][32];               // 2 KB
  __shared__ float wsum[8];

  const int t = threadIdx.x;
  const int w = t >> 6;
  const int lane = t & 63;
  const int lhi = lane >> 5;
  const int llo = lane & 31;
  const int bx = blockIdx.x;
  const int i0 = (bx >> 4) * 2;
  const int j0 = (bx & 15) * 32;

  // ---- epilogue invariants ----
  const float SCALE = (0.25f / (127.0f * 127.0f)) * C2;
  float b2c[2], w3v[2];
#pragma unroll
  for (int ntl = 0; ntl < 2; ++ntl) {
    const int n = w * 64 + ntl * 32 + llo;
    b2c[ntl] = b2[n] * C2;
    w3v[ntl] = W3[n];
  }
  {
    float w3s = w3v[0] + w3v[1];
#pragma unroll
    for (int off = 1; off < 32; off <<= 1) w3s += __shfl_xor(w3s, off, 64);
    if (lane == 0) wsum[w] = w3s;  // visible after the staging barrier
  }

  // ---- stage X for both i's: thread t -> row = t&31, slots {t>>5, (t>>5)+16} (16 k each) ----
  {
    const int srow = t & 31;
    const int ss0 = t >> 5;  // 0..15
    const int k0 = ss0 * 16;
    const float* ajr = Aj + (size_t)(j0 + srow) * NH;
    const float* air0 = Ai + (size_t)i0 * NH;
    const float* air1 = Ai + (size_t)(i0 + 1) * NH;
    u32 wd0[8], wd1[8];
#pragma unroll
    for (int g = 0; g < 8; ++g) {
      const int ko = k0 + (g & 3) * 4 + (g >> 2) * 256;
      const float4 fa = *(const float4*)(ajr + ko);
      const float4 g0 = *(const float4*)(air0 + ko);
      const float4 g1 = *(const float4*)(air1 + ko);
      {
        const u32 m0 = tanh_q127_magic(fa.x + g0.x);
        const u32 m1 = tanh_q127_magic(fa.y + g0.y);
        const u32 m2 = tanh_q127_magic(fa.z + g0.z);
        const u32 m3 = tanh_q127_magic(fa.w + g0.w);
        const u32 p01 = perm_b32(m1, m0, 0x0C0C0400u);
        const u32 p23 = perm_b32(m3, m2, 0x0C0C0400u);
        wd0[g] = perm_b32(p23, p01, 0x05040100u);
      }
      {
        const u32 m0 = tanh_q127_magic(fa.x + g1.x);
        const u32 m1 = tanh_q127_magic(fa.y + g1.y);
        const u32 m2 = tanh_q127_magic(fa.z + g1.z);
        const u32 m3 = tanh_q127_magic(fa.w + g1.w);
        const u32 p01 = perm_b32(m1, m0, 0x0C0C0400u);
        const u32 p23 = perm_b32(m3, m2, 0x0C0C0400u);
        wd1[g] = perm_b32(p23, p01, 0x05040100u);
      }
    }
    ((uint4*)xs[0])[ss0 * 32 + srow] = make_uint4(wd0[0], wd0[1], wd0[2], wd0[3]);
    ((uint4*)xs[0])[(ss0 + 16) * 32 + srow] = make_uint4(wd0[4], wd0[5], wd0[6], wd0[7]);
    ((uint4*)xs[1])[ss0 * 32 + srow] = make_uint4(wd1[0], wd1[1], wd1[2], wd1[3]);
    ((uint4*)xs[1])[(ss0 + 16) * 32 + srow] = make_uint4(wd1[4], wd1[5], wd1[6], wd1[7]);
  }
  __syncthreads();

  // ---- K-loop: per ks, 2 B-loads + 2 A-reads -> 4 MFMAs; prefetch distance 2 ----
  i32x16 acc[2][2];  // [i][ntl]
#pragma unroll
  for (int ii = 0; ii < 2; ++ii)
#pragma unroll
    for (int nt = 0; nt < 2; ++nt)
#pragma unroll
      for (int q = 0; q < 16; ++q) acc[ii][nt][q] = 0;

  {
    const i32x4* xv0 = (const i32x4*)xs[0];
    const i32x4* xv1 = (const i32x4*)xs[1];
    const int abase = lhi * 32 + llo;                       // + ks*64
    const uint4* w2v = (const uint4*)W2q + w * 128 + lane;  // + ks*1024, +64 for ntl=1

    // 2-deep circular pipeline (parity p = ks&1), SSA via full unroll
    i32x4 a0[2], a1[2];
    uint4 b0[2], b1[2];
    a0[0] = xv0[abase];
    a1[0] = xv1[abase];
    a0[1] = xv0[64 + abase];
    a1[1] = xv1[64 + abase];
    b0[0] = w2v[0];
    b1[0] = w2v[64];
    b0[1] = w2v[1024];
    b1[1] = w2v[1024 + 64];

#pragma unroll
    for (int ks = 0; ks < 16; ++ks) {
      const int p = ks & 1;
      const i32x4 aa0 = a0[p];
      const i32x4 aa1 = a1[p];
      const i32x4 c0 = __builtin_bit_cast(i32x4, b0[p]);
      const i32x4 c1 = __builtin_bit_cast(i32x4, b1[p]);
      if (ks < 14) {
        a0[p] = xv0[(ks + 2) * 64 + abase];
        a1[p] = xv1[(ks + 2) * 64 + abase];
        const uint4* wp = w2v + (ks + 2) * 1024;
        b0[p] = wp[0];
        b1[p] = wp[64];
      }
      acc[0][0] = __builtin_amdgcn_mfma_i32_32x32x32_i8(aa0, c0, acc[0][0], 0, 0, 0);
      acc[0][1] = __builtin_amdgcn_mfma_i32_32x32x32_i8(aa0, c1, acc[0][1], 0, 0, 0);
      acc[1][0] = __builtin_amdgcn_mfma_i32_32x32x32_i8(aa1, c0, acc[1][0], 0, 0, 0);
      acc[1][1] = __builtin_amdgcn_mfma_i32_32x32x32_i8(aa1, c1, acc[1][1], 0, 0, 0);
    }
  }

  // ---- epilogue per i: y = acc*SCALE + b2*C2; r = 1/(exp2(y)+1); partial = Σw3 - 2 Σ w3·r ----
#pragma unroll
  for (int ii = 0; ii < 2; ++ii) {
#pragma unroll
    for (int reg = 0; reg < 16; ++reg) {
      float sr = 0.0f;
#pragma unroll
      for (int ntl = 0; ntl < 2; ++ntl) {
        const float y = fmaf((float)acc[ii][ntl][reg], SCALE, b2c[ntl]);
        const float r = rcp_fast(exp2_fast(y) + 1.0f);
        sr = fmaf(w3v[ntl], r, sr);
      }
#pragma unroll
      for (int off = 1; off < 32; off <<= 1) sr += __shfl_xor(sr, off, 64);
      const int row = (reg & 3) + 8 * (reg >> 2) + 4 * lhi;  // 0..31
      if (llo == reg) red[ii][w][row] = -2.0f * sr;          // w3s added at write-out
    }
  }
  __syncthreads();

  // ---- write-out: t<64 -> (ii = t>>5, row = t&31) ----
  if (t < 64) {
    const int ii = t >> 5;
    const int row = t & 31;
    float v = b3[0] + ((wsum[0] + wsum[1]) + (wsum[2] + wsum[3])) +
              ((wsum[4] + wsum[5]) + (wsum[6] + wsum[7]));
#pragma unroll
    for (int ww = 0; ww < 8; ++ww) v += red[ii][ww][row];
    const int icur = i0 + ii;
    const int j = j0 + row;
    out[icur * NB + j] = (j == icur) ? -20.0f : v;
  }
}

extern "C" void kernel_launch(void* const* d_in, const int* in_sizes, int n_in,
                              void* d_out, int out_size, void* d_ws, size_t ws_size,
                              hipStream_t stream) {
  const float* h = (const float*)d_in[0];
  const float* W1 = (const float*)d_in[1];
  const float* b1 = (const float*)d_in[2];
  const float* W2 = (const float*)d_in[3];
  const float* b2 = (const float*)d_in[4];
  const float* W3 = (const float*)d_in[5];
  const float* b3 = (const float*)d_in[6];
  float* out = (float*)d_out;

  float* Ai = (float*)d_ws;
  float* Aj = Ai + NB * NH;
  u8* W2q = (u8*)(Aj + NB * NH);

  prep_all<<<320, 256, 0, stream>>>(h, W1, b1, W2, Ai, Aj, W2q);
  pair_main<<<4096, 512, 0, stream>>>(Ai, Aj, W2q, b2, W3, b3, out);
}